// Round 15
// baseline (366.532 us; speedup 1.0000x reference)
//
#include <hip/hip_runtime.h>
#include <hip/hip_bf16.h>

#define B_DIM 512
#define T_DIM 512
#define IND 64
#define WIDTH 128
#define GAMMA 0.01f
#define EPS 0.01f

// ---------------------------------------------------------------------------
// Kernel 1: projection  out[m][w] = b[w] + sum_i x[m][i] * V[i][w]
// (unchanged: near BW roofline)
// ---------------------------------------------------------------------------
#define PJ_ROWS 16
#define PJ_NT ((B_DIM * T_DIM) / PJ_ROWS)  // 16384

__global__ __launch_bounds__(256) void proj_kernel(
    const float* __restrict__ x, const float* __restrict__ V,
    const float* __restrict__ bias, float* __restrict__ out) {
  __shared__ __align__(16) float xs[PJ_ROWS * IND];  // 4 KB

  const int tid = threadIdx.x;
  const int c2 = (tid & 63) * 2;
  const int rh = tid >> 6;

  float2 Vreg[IND];
#pragma unroll
  for (int k = 0; k < IND; ++k)
    Vreg[k] = *(const float2*)(V + k * WIDTH + c2);
  const float2 bb = *(const float2*)(bias + c2);

  for (int tile = blockIdx.x; tile < PJ_NT; tile += gridDim.x) {
    const size_t m0 = (size_t)tile * PJ_ROWS;
    __syncthreads();
#pragma unroll
    for (int q = 0; q < 4; ++q)
      xs[tid + 256 * q] = x[m0 * IND + tid + 256 * q];
    __syncthreads();

    float2 acc0 = bb, acc1 = bb, acc2 = bb, acc3 = bb;
#pragma unroll
    for (int k4 = 0; k4 < IND / 4; ++k4) {
      float4 xv0 = ((const float4*)&xs[(rh + 0) * IND])[k4];
      float4 xv1 = ((const float4*)&xs[(rh + 4) * IND])[k4];
      float4 xv2 = ((const float4*)&xs[(rh + 8) * IND])[k4];
      float4 xv3 = ((const float4*)&xs[(rh + 12) * IND])[k4];
#pragma unroll
      for (int j = 0; j < 4; ++j) {
        float2 v = Vreg[4 * k4 + j];
        float e0 = (j == 0) ? xv0.x : (j == 1) ? xv0.y : (j == 2) ? xv0.z : xv0.w;
        float e1 = (j == 0) ? xv1.x : (j == 1) ? xv1.y : (j == 2) ? xv1.z : xv1.w;
        float e2 = (j == 0) ? xv2.x : (j == 1) ? xv2.y : (j == 2) ? xv2.z : xv2.w;
        float e3 = (j == 0) ? xv3.x : (j == 1) ? xv3.y : (j == 2) ? xv3.z : xv3.w;
        acc0.x += e0 * v.x; acc0.y += e0 * v.y;
        acc1.x += e1 * v.x; acc1.y += e1 * v.y;
        acc2.x += e2 * v.x; acc2.y += e2 * v.y;
        acc3.x += e3 * v.x; acc3.y += e3 * v.y;
      }
    }
    *(float2*)(out + (m0 + rh + 0) * WIDTH + c2) = acc0;
    *(float2*)(out + (m0 + rh + 4) * WIDTH + c2) = acc1;
    *(float2*)(out + (m0 + rh + 8) * WIDTH + c2) = acc2;
    *(float2*)(out + (m0 + rh + 12) * WIDTH + c2) = acc3;
  }
}

// ---------------------------------------------------------------------------
// Kernel 2: recurrence — ncols=4 x ksplit=8 (R12 geometry) with the two
// diagnosed fixes:
// (1) __launch_bounds__(256, 2): we only ever run 2 waves/SIMD (512 blocks x
//     4 waves / 1024 SIMDs), so the VGPR cap can be ~256. R12/R13's default
//     cap of 88 < ~160 live demand caused remat/shuffle bloat (measured
//     ~1030 VALU-cy/SIMD/step vs ~460 expected) — the geometry never got a
//     fair test.
// (2) xor-4 reduce stage = ONE row_shl:4 DPP (dest lane i <- src lane i+4):
//     after xor1+xor2 the partial is quad-uniform, so this hands quads
//     kc=0..3 their kc=4..7 partner's partial. Only kc==0 lanes need the
//     true sum (they alone store; other lanes' tails are dead).
// Interleaved k-chunks (kc owns float4-slots {kc, kc+8, kc+16, kc+24}):
// slot%8==kc -> 8 distinct bank-groups, conflict-free (0 in R12/R13 PMC).
// DS/CU-step: 32 b128 reads + 8 b128 writes (half of R11's 64+8).
// Deep U=8 chunked u prefetch (R11, proven). lgkm-only barrier.
// ---------------------------------------------------------------------------
#define LDS_BARRIER() asm volatile("s_waitcnt lgkmcnt(0)\n\ts_barrier" ::: "memory")

template <int CTRL>
__device__ __forceinline__ float dpp_mov(float x) {
  return __int_as_float(
      __builtin_amdgcn_update_dpp(0, __float_as_int(x), CTRL, 0xf, 0xf, true));
}

__global__ __launch_bounds__(256, 2) void rnn_kernel(
    const float* __restrict__ W, const float* __restrict__ init,
    float* __restrict__ out, float* __restrict__ finals) {
  __shared__ __align__(16) float sL[2][WIDTH];
  const int b = blockIdx.x;
  const int tid = threadIdx.x;
  const int kc = tid & 7;    // k-chunk id = lane bits 0-2
  const int c4 = tid >> 3;   // 0..31 column quad
  const int c0 = 4 * c4;     // columns c0..c0+3

  // Interleaved chunk: kc owns k in { j*32 + kc*4 + m : j=0..3, m=0..3 }.
  // Areg[col][4j+m] = A'[j*32+kc*4+m][c0+col],  A' = W - W^T - gamma*I.
  float Areg[4][16];
#pragma unroll
  for (int j = 0; j < 4; ++j) {
    const int k = j * 32 + kc * 4;
#pragma unroll
    for (int col = 0; col < 4; ++col) {
      const int cc = c0 + col;
      float4 wr = *(const float4*)(W + (size_t)cc * WIDTH + k);  // W[cc][k..k+3]
      float a0 = W[(size_t)(k + 0) * WIDTH + cc] - wr.x;
      float a1 = W[(size_t)(k + 1) * WIDTH + cc] - wr.y;
      float a2 = W[(size_t)(k + 2) * WIDTH + cc] - wr.z;
      float a3 = W[(size_t)(k + 3) * WIDTH + cc] - wr.w;
      if (k + 0 == cc) a0 -= GAMMA;
      if (k + 1 == cc) a1 -= GAMMA;
      if (k + 2 == cc) a2 -= GAMMA;
      if (k + 3 == cc) a3 -= GAMMA;
      Areg[col][4 * j + 0] = a0;
      Areg[col][4 * j + 1] = a1;
      Areg[col][4 * j + 2] = a2;
      Areg[col][4 * j + 3] = a3;
    }
  }

  float4 s = *(const float4*)(init + (size_t)b * WIDTH + c0);
  if (kc == 0) *(float4*)&sL[0][c0] = s;
  __syncthreads();

  float* outc = out + (size_t)b * T_DIM * WIDTH + c0;

  // Deep chunked u prefetch (U=8): uA consumed, uB in flight.
  float4 uA[8], uB[8];
#pragma unroll
  for (int tt = 0; tt < 8; ++tt) {
    uA[tt] = *(const float4*)(outc + (size_t)tt * WIDTH);
    uB[tt] = *(const float4*)(outc + (size_t)(tt + 8) * WIDTH);
  }

#pragma unroll 1
  for (int tc = 0; tc < T_DIM; tc += 8) {
#pragma unroll
    for (int tt = 0; tt < 8; ++tt) {
      const int p = tt & 1;  // compile-time LDS parity
      const float4 u = uA[tt];

      const float4* sp = (const float4*)&sL[p][0];
      // 4 b128 reads at slots j*8+kc -> bank-group kc, conflict-free
      float4 sv0 = sp[0 * 8 + kc];
      float4 sv1 = sp[1 * 8 + kc];
      float4 sv2 = sp[2 * 8 + kc];
      float4 sv3 = sp[3 * 8 + kc];

      float a0[4], a1[4];
#pragma unroll
      for (int col = 0; col < 4; ++col) {
        a0[col] = sv0.x * Areg[col][0] + sv0.z * Areg[col][2];
        a1[col] = sv0.y * Areg[col][1] + sv0.w * Areg[col][3];
        a0[col] += sv1.x * Areg[col][4] + sv1.z * Areg[col][6];
        a1[col] += sv1.y * Areg[col][5] + sv1.w * Areg[col][7];
        a0[col] += sv2.x * Areg[col][8] + sv2.z * Areg[col][10];
        a1[col] += sv2.y * Areg[col][9] + sv2.w * Areg[col][11];
        a0[col] += sv3.x * Areg[col][12] + sv3.z * Areg[col][14];
        a1[col] += sv3.y * Areg[col][13] + sv3.w * Areg[col][15];
      }
      float d[4];
#pragma unroll
      for (int col = 0; col < 4; ++col) d[col] = a0[col] + a1[col];
      // 8-way split-k reduce over lane bits 0-2 (pure VALU, 3 DPP/col):
      // xor1, xor2 -> quad-uniform; row_shl:4 hands kc<4 quads the kc>=4
      // partial. Only kc==0 lanes need the true sum (they alone store).
#pragma unroll
      for (int col = 0; col < 4; ++col) d[col] += dpp_mov<0xB1>(d[col]);
#pragma unroll
      for (int col = 0; col < 4; ++col) d[col] += dpp_mov<0x4E>(d[col]);
#pragma unroll
      for (int col = 0; col < 4; ++col) d[col] += dpp_mov<0x104>(d[col]);

      float* sa = (float*)&s;
      const float* ua = (const float*)&u;
#pragma unroll
      for (int col = 0; col < 4; ++col) {
        const float f = d[col] + ua[col];  // gamma folded into A'
        // tanh(f) = 1 - 2/(exp(2f)+1); inf-safe both directions
        const float e = __expf(2.0f * f);
        const float th = fmaf(-2.0f, __builtin_amdgcn_rcpf(e + 1.0f), 1.0f);
        sa[col] = fmaf(EPS, th, sa[col]);
      }

      if (kc == 0) {
        *(float4*)(outc + (size_t)(tc + tt) * WIDTH) = s;  // overwrite u slot
        *(float4*)&sL[p ^ 1][c0] = s;
      }
      LDS_BARRIER();  // lgkm-only drain; globals stay in flight
    }

    // rotate; issue loads for steps tc+16..tc+23 (slack ~8 steps >> L).
    // Unclamped tail reads land in the finals region of d_out (512 rows),
    // never consumed.
#pragma unroll
    for (int tt = 0; tt < 8; ++tt) {
      uA[tt] = uB[tt];
      uB[tt] = *(const float4*)(outc + (size_t)(tc + 16 + tt) * WIDTH);
    }
  }

  if (kc == 0) *(float4*)(finals + (size_t)b * WIDTH + c0) = s;
}

extern "C" void kernel_launch(void* const* d_in, const int* in_sizes, int n_in,
                              void* d_out, int out_size, void* d_ws,
                              size_t ws_size, hipStream_t stream) {
  const float* x = (const float*)d_in[0];
  const float* init = (const float*)d_in[1];
  const float* W = (const float*)d_in[2];
  const float* V = (const float*)d_in[3];
  const float* bias = (const float*)d_in[4];

  float* out = (float*)d_out;
  float* finals = out + (size_t)B_DIM * T_DIM * WIDTH;

  proj_kernel<<<2048, 256, 0, stream>>>(x, V, bias, out);
  rnn_kernel<<<B_DIM, 256, 0, stream>>>(W, init, out, finals);
}

// Round 16
// 271.625 us; speedup vs baseline: 1.3494x; 1.3494x over previous
//
#include <hip/hip_runtime.h>
#include <hip/hip_bf16.h>

#define B_DIM 512
#define T_DIM 512
#define IND 64
#define WIDTH 128
#define GAMMA 0.01f
#define EPS 0.01f

// ---------------------------------------------------------------------------
// Kernel 1: projection  out[m][w] = b[w] + sum_i x[m][i] * V[i][w]
// (unchanged: near BW roofline)
// ---------------------------------------------------------------------------
#define PJ_ROWS 16
#define PJ_NT ((B_DIM * T_DIM) / PJ_ROWS)  // 16384

__global__ __launch_bounds__(256) void proj_kernel(
    const float* __restrict__ x, const float* __restrict__ V,
    const float* __restrict__ bias, float* __restrict__ out) {
  __shared__ __align__(16) float xs[PJ_ROWS * IND];  // 4 KB

  const int tid = threadIdx.x;
  const int c2 = (tid & 63) * 2;
  const int rh = tid >> 6;

  float2 Vreg[IND];
#pragma unroll
  for (int k = 0; k < IND; ++k)
    Vreg[k] = *(const float2*)(V + k * WIDTH + c2);
  const float2 bb = *(const float2*)(bias + c2);

  for (int tile = blockIdx.x; tile < PJ_NT; tile += gridDim.x) {
    const size_t m0 = (size_t)tile * PJ_ROWS;
    __syncthreads();
#pragma unroll
    for (int q = 0; q < 4; ++q)
      xs[tid + 256 * q] = x[m0 * IND + tid + 256 * q];
    __syncthreads();

    float2 acc0 = bb, acc1 = bb, acc2 = bb, acc3 = bb;
#pragma unroll
    for (int k4 = 0; k4 < IND / 4; ++k4) {
      float4 xv0 = ((const float4*)&xs[(rh + 0) * IND])[k4];
      float4 xv1 = ((const float4*)&xs[(rh + 4) * IND])[k4];
      float4 xv2 = ((const float4*)&xs[(rh + 8) * IND])[k4];
      float4 xv3 = ((const float4*)&xs[(rh + 12) * IND])[k4];
#pragma unroll
      for (int j = 0; j < 4; ++j) {
        float2 v = Vreg[4 * k4 + j];
        float e0 = (j == 0) ? xv0.x : (j == 1) ? xv0.y : (j == 2) ? xv0.z : xv0.w;
        float e1 = (j == 0) ? xv1.x : (j == 1) ? xv1.y : (j == 2) ? xv1.z : xv1.w;
        float e2 = (j == 0) ? xv2.x : (j == 1) ? xv2.y : (j == 2) ? xv2.z : xv2.w;
        float e3 = (j == 0) ? xv3.x : (j == 1) ? xv3.y : (j == 2) ? xv3.z : xv3.w;
        acc0.x += e0 * v.x; acc0.y += e0 * v.y;
        acc1.x += e1 * v.x; acc1.y += e1 * v.y;
        acc2.x += e2 * v.x; acc2.y += e2 * v.y;
        acc3.x += e3 * v.x; acc3.y += e3 * v.y;
      }
    }
    *(float2*)(out + (m0 + rh + 0) * WIDTH + c2) = acc0;
    *(float2*)(out + (m0 + rh + 4) * WIDTH + c2) = acc1;
    *(float2*)(out + (m0 + rh + 8) * WIDTH + c2) = acc2;
    *(float2*)(out + (m0 + rh + 12) * WIDTH + c2) = acc3;
  }
}

// ---------------------------------------------------------------------------
// Kernel 2: recurrence = R11 (proven best: ncols=2, split-k=4, tight codegen)
// with three codegen-preserving micro-opts:
// (1) gamma folded into A' diagonal  -> f = d + u (2 fewer FMAs/thread/step)
// (2) tanh via exp2f(f * 2/ln2)      -> 1 mul + v_exp (was 2 muls)
// (3) in-place depth-8 u prefetch: uA[tt] refilled with step t+8's value
//     right after step t's is consumed — no rotation movs, half the u regs,
//     loads spread across steps. Tail overreads land in the finals region
//     of d_out (written later by this same block), never consumed.
// Geometry (unchanged): 256 thr/block = (colpair cp 0..63, kc 0..3),
// bank-staggered b128 broadcast reads (0 conflicts), DPP quad reduce,
// double-buffered sL, lgkm-only barrier, kc==0 stores.
// ---------------------------------------------------------------------------
#define LDS_BARRIER() asm volatile("s_waitcnt lgkmcnt(0)\n\ts_barrier" ::: "memory")

template <int CTRL>
__device__ __forceinline__ float dpp_mov(float x) {
  return __int_as_float(
      __builtin_amdgcn_update_dpp(0, __float_as_int(x), CTRL, 0xf, 0xf, true));
}

__global__ __launch_bounds__(256) void rnn_kernel(
    const float* __restrict__ W, const float* __restrict__ init,
    float* __restrict__ out, float* __restrict__ finals) {
  __shared__ __align__(16) float sL[2][WIDTH];
  const int b = blockIdx.x;
  const int tid = threadIdx.x;
  const int kc = tid & 3;   // k-chunk, lane bits 0-1
  const int cp = tid >> 2;  // 0..63 column pair
  const int c0 = 2 * cp;

  // Areg[col][4j+m] = A'[kc*32 + ((j+2kc)&7)*4 + m][c0+col]
  // A' = W - W^T - gamma*I  (bank-stagger rotation baked in)
  float Areg[2][32];
  {
    const int k0 = kc * 32;
#pragma unroll
    for (int j = 0; j < 8; ++j) {
      const int ri = (j + 2 * kc) & 7;  // runtime, addresses only
      const int k = k0 + ri * 4;
#pragma unroll
      for (int col = 0; col < 2; ++col) {
        const int cc = c0 + col;
        float4 wr = *(const float4*)(W + (size_t)cc * WIDTH + k);
        float a0 = W[(size_t)(k + 0) * WIDTH + cc] - wr.x;
        float a1 = W[(size_t)(k + 1) * WIDTH + cc] - wr.y;
        float a2 = W[(size_t)(k + 2) * WIDTH + cc] - wr.z;
        float a3 = W[(size_t)(k + 3) * WIDTH + cc] - wr.w;
        if (k + 0 == cc) a0 -= GAMMA;
        if (k + 1 == cc) a1 -= GAMMA;
        if (k + 2 == cc) a2 -= GAMMA;
        if (k + 3 == cc) a3 -= GAMMA;
        Areg[col][4 * j + 0] = a0;
        Areg[col][4 * j + 1] = a1;
        Areg[col][4 * j + 2] = a2;
        Areg[col][4 * j + 3] = a3;
      }
    }
  }

  float2 s = *(const float2*)(init + (size_t)b * WIDTH + c0);
  if (kc == 0) *(float2*)&sL[0][c0] = s;
  __syncthreads();

  float* outc = out + (size_t)b * T_DIM * WIDTH + c0;

  // In-place depth-8 u prefetch: uA[tt] holds step (tc+tt)'s u.
  float2 uA[8];
#pragma unroll
  for (int tt = 0; tt < 8; ++tt)
    uA[tt] = *(const float2*)(outc + (size_t)tt * WIDTH);

#pragma unroll 1
  for (int tc = 0; tc < T_DIM; tc += 8) {
#pragma unroll
    for (int tt = 0; tt < 8; ++tt) {
      const int p = tt & 1;  // compile-time LDS parity
      const float2 u = uA[tt];
      // refill with step (tc+tt+8)'s u — 8-step slack; tail reads land in
      // the finals region of d_out (never consumed).
      uA[tt] = *(const float2*)(outc + (size_t)(tc + tt + 8) * WIDTH);

      const float4* sp = (const float4*)&sL[p][0];
      float a00 = 0.f, a01 = 0.f, a10 = 0.f, a11 = 0.f;
#pragma unroll
      for (int j = 0; j < 8; ++j) {
        const int ri = (j + 2 * kc) & 7;  // bank-staggered (0 conflicts)
        float4 sv = sp[kc * 8 + ri];
        a00 += sv.x * Areg[0][4 * j + 0];
        a01 += sv.y * Areg[0][4 * j + 1];
        a00 += sv.z * Areg[0][4 * j + 2];
        a01 += sv.w * Areg[0][4 * j + 3];
        a10 += sv.x * Areg[1][4 * j + 0];
        a11 += sv.y * Areg[1][4 * j + 1];
        a10 += sv.z * Areg[1][4 * j + 2];
        a11 += sv.w * Areg[1][4 * j + 3];
      }
      float d0 = a00 + a01;
      float d1 = a10 + a11;
      // 4-way split-k sum over lane bits 0-1 via DPP (pure VALU)
      d0 += dpp_mov<0xB1>(d0);
      d1 += dpp_mov<0xB1>(d1);
      d0 += dpp_mov<0x4E>(d0);
      d1 += dpp_mov<0x4E>(d1);

      const float f0 = d0 + u.x;  // gamma folded into A'
      const float f1 = d1 + u.y;
      // tanh(f) = 1 - 2/(e^{2f}+1); e^{2f} = 2^(f*2/ln2); inf-safe
      const float e0 = exp2f(f0 * 2.8853900817779268f);
      const float e1 = exp2f(f1 * 2.8853900817779268f);
      const float th0 = fmaf(-2.0f, __builtin_amdgcn_rcpf(e0 + 1.0f), 1.0f);
      const float th1 = fmaf(-2.0f, __builtin_amdgcn_rcpf(e1 + 1.0f), 1.0f);
      s.x = fmaf(EPS, th0, s.x);
      s.y = fmaf(EPS, th1, s.y);

      if (kc == 0) {
        *(float2*)(outc + (size_t)(tc + tt) * WIDTH) = s;  // overwrite u slot
        *(float2*)&sL[p ^ 1][c0] = s;
      }
      LDS_BARRIER();  // lgkm-only drain; globals stay in flight
    }
  }

  if (kc == 0) *(float2*)(finals + (size_t)b * WIDTH + c0) = s;
}

extern "C" void kernel_launch(void* const* d_in, const int* in_sizes, int n_in,
                              void* d_out, int out_size, void* d_ws,
                              size_t ws_size, hipStream_t stream) {
  const float* x = (const float*)d_in[0];
  const float* init = (const float*)d_in[1];
  const float* W = (const float*)d_in[2];
  const float* V = (const float*)d_in[3];
  const float* bias = (const float*)d_in[4];

  float* out = (float*)d_out;
  float* finals = out + (size_t)B_DIM * T_DIM * WIDTH;

  proj_kernel<<<2048, 256, 0, stream>>>(x, V, bias, out);
  rnn_kernel<<<B_DIM, 256, 0, stream>>>(W, init, out, finals);
}

// Round 17
// 262.887 us; speedup vs baseline: 1.3943x; 1.0332x over previous
//
#include <hip/hip_runtime.h>
#include <hip/hip_bf16.h>

#define B_DIM 512
#define T_DIM 512
#define IND 64
#define WIDTH 128
#define GAMMA 0.01f
#define EPS 0.01f

// ---------------------------------------------------------------------------
// Kernel 1: projection  out[m][w] = b[w] + sum_i x[m][i] * V[i][w]
// R17: double-buffered x staging — issue tile i+1's loads BEFORE computing
// tile i; ONE barrier per tile (was two). float4 global loads (16B/lane).
// Write/read of the two xs buffers never overlap within an iteration, and
// the end-of-iteration barrier separates reuse across iterations.
// ---------------------------------------------------------------------------
#define PJ_ROWS 16
#define PJ_NT ((B_DIM * T_DIM) / PJ_ROWS)  // 16384
#define PJ_GRID 2048

__global__ __launch_bounds__(256) void proj_kernel(
    const float* __restrict__ x, const float* __restrict__ V,
    const float* __restrict__ bias, float* __restrict__ out) {
  __shared__ __align__(16) float xs[2][PJ_ROWS * IND];  // 2 x 4 KB

  const int tid = threadIdx.x;
  const int c2 = (tid & 63) * 2;
  const int rh = tid >> 6;

  float2 Vreg[IND];
#pragma unroll
  for (int k = 0; k < IND; ++k)
    Vreg[k] = *(const float2*)(V + k * WIDTH + c2);
  const float2 bb = *(const float2*)(bias + c2);

  // prologue: stage first tile
  int p = 0;
  {
    const size_t m0 = (size_t)blockIdx.x * PJ_ROWS;
    *(float4*)&xs[0][tid * 4] = *(const float4*)(x + m0 * IND + tid * 4);
  }
  __syncthreads();

  for (int tile = blockIdx.x; tile < PJ_NT; tile += PJ_GRID) {
    const int nxt = tile + PJ_GRID;
    if (nxt < PJ_NT) {  // prefetch next tile into the other buffer
      const size_t m1 = (size_t)nxt * PJ_ROWS;
      *(float4*)&xs[p ^ 1][tid * 4] = *(const float4*)(x + m1 * IND + tid * 4);
    }

    const size_t m0 = (size_t)tile * PJ_ROWS;
    float2 acc0 = bb, acc1 = bb, acc2 = bb, acc3 = bb;
#pragma unroll
    for (int k4 = 0; k4 < IND / 4; ++k4) {
      float4 xv0 = ((const float4*)&xs[p][(rh + 0) * IND])[k4];
      float4 xv1 = ((const float4*)&xs[p][(rh + 4) * IND])[k4];
      float4 xv2 = ((const float4*)&xs[p][(rh + 8) * IND])[k4];
      float4 xv3 = ((const float4*)&xs[p][(rh + 12) * IND])[k4];
#pragma unroll
      for (int j = 0; j < 4; ++j) {
        float2 v = Vreg[4 * k4 + j];
        float e0 = (j == 0) ? xv0.x : (j == 1) ? xv0.y : (j == 2) ? xv0.z : xv0.w;
        float e1 = (j == 0) ? xv1.x : (j == 1) ? xv1.y : (j == 2) ? xv1.z : xv1.w;
        float e2 = (j == 0) ? xv2.x : (j == 1) ? xv2.y : (j == 2) ? xv2.z : xv2.w;
        float e3 = (j == 0) ? xv3.x : (j == 1) ? xv3.y : (j == 2) ? xv3.z : xv3.w;
        acc0.x += e0 * v.x; acc0.y += e0 * v.y;
        acc1.x += e1 * v.x; acc1.y += e1 * v.y;
        acc2.x += e2 * v.x; acc2.y += e2 * v.y;
        acc3.x += e3 * v.x; acc3.y += e3 * v.y;
      }
    }
    *(float2*)(out + (m0 + rh + 0) * WIDTH + c2) = acc0;
    *(float2*)(out + (m0 + rh + 4) * WIDTH + c2) = acc1;
    *(float2*)(out + (m0 + rh + 8) * WIDTH + c2) = acc2;
    *(float2*)(out + (m0 + rh + 12) * WIDTH + c2) = acc3;

    __syncthreads();  // staging writes visible; old buffer free next iter
    p ^= 1;
  }
}

// ---------------------------------------------------------------------------
// Kernel 2: recurrence (R16 — structural ceiling at ~1040 cy/step).
// ncols=2, split-k=4, bank-staggered b128 broadcast reads (0 conflicts),
// DPP quad reduce, gamma folded into A', exp2-based tanh, in-place depth-8
// u prefetch, double-buffered sL, lgkm-only barrier.
// ---------------------------------------------------------------------------
#define LDS_BARRIER() asm volatile("s_waitcnt lgkmcnt(0)\n\ts_barrier" ::: "memory")

template <int CTRL>
__device__ __forceinline__ float dpp_mov(float x) {
  return __int_as_float(
      __builtin_amdgcn_update_dpp(0, __float_as_int(x), CTRL, 0xf, 0xf, true));
}

__global__ __launch_bounds__(256) void rnn_kernel(
    const float* __restrict__ W, const float* __restrict__ init,
    float* __restrict__ out, float* __restrict__ finals) {
  __shared__ __align__(16) float sL[2][WIDTH];
  const int b = blockIdx.x;
  const int tid = threadIdx.x;
  const int kc = tid & 3;   // k-chunk, lane bits 0-1
  const int cp = tid >> 2;  // 0..63 column pair
  const int c0 = 2 * cp;

  // Areg[col][4j+m] = A'[kc*32 + ((j+2kc)&7)*4 + m][c0+col]
  // A' = W - W^T - gamma*I  (bank-stagger rotation baked in)
  float Areg[2][32];
  {
    const int k0 = kc * 32;
#pragma unroll
    for (int j = 0; j < 8; ++j) {
      const int ri = (j + 2 * kc) & 7;  // runtime, addresses only
      const int k = k0 + ri * 4;
#pragma unroll
      for (int col = 0; col < 2; ++col) {
        const int cc = c0 + col;
        float4 wr = *(const float4*)(W + (size_t)cc * WIDTH + k);
        float a0 = W[(size_t)(k + 0) * WIDTH + cc] - wr.x;
        float a1 = W[(size_t)(k + 1) * WIDTH + cc] - wr.y;
        float a2 = W[(size_t)(k + 2) * WIDTH + cc] - wr.z;
        float a3 = W[(size_t)(k + 3) * WIDTH + cc] - wr.w;
        if (k + 0 == cc) a0 -= GAMMA;
        if (k + 1 == cc) a1 -= GAMMA;
        if (k + 2 == cc) a2 -= GAMMA;
        if (k + 3 == cc) a3 -= GAMMA;
        Areg[col][4 * j + 0] = a0;
        Areg[col][4 * j + 1] = a1;
        Areg[col][4 * j + 2] = a2;
        Areg[col][4 * j + 3] = a3;
      }
    }
  }

  float2 s = *(const float2*)(init + (size_t)b * WIDTH + c0);
  if (kc == 0) *(float2*)&sL[0][c0] = s;
  __syncthreads();

  float* outc = out + (size_t)b * T_DIM * WIDTH + c0;

  // In-place depth-8 u prefetch: uA[tt] holds step (tc+tt)'s u.
  float2 uA[8];
#pragma unroll
  for (int tt = 0; tt < 8; ++tt)
    uA[tt] = *(const float2*)(outc + (size_t)tt * WIDTH);

#pragma unroll 1
  for (int tc = 0; tc < T_DIM; tc += 8) {
#pragma unroll
    for (int tt = 0; tt < 8; ++tt) {
      const int p = tt & 1;  // compile-time LDS parity
      const float2 u = uA[tt];
      // refill with step (tc+tt+8)'s u — 8-step slack; tail reads land in
      // the finals region of d_out (never consumed).
      uA[tt] = *(const float2*)(outc + (size_t)(tc + tt + 8) * WIDTH);

      const float4* sp = (const float4*)&sL[p][0];
      float a00 = 0.f, a01 = 0.f, a10 = 0.f, a11 = 0.f;
#pragma unroll
      for (int j = 0; j < 8; ++j) {
        const int ri = (j + 2 * kc) & 7;  // bank-staggered (0 conflicts)
        float4 sv = sp[kc * 8 + ri];
        a00 += sv.x * Areg[0][4 * j + 0];
        a01 += sv.y * Areg[0][4 * j + 1];
        a00 += sv.z * Areg[0][4 * j + 2];
        a01 += sv.w * Areg[0][4 * j + 3];
        a10 += sv.x * Areg[1][4 * j + 0];
        a11 += sv.y * Areg[1][4 * j + 1];
        a10 += sv.z * Areg[1][4 * j + 2];
        a11 += sv.w * Areg[1][4 * j + 3];
      }
      float d0 = a00 + a01;
      float d1 = a10 + a11;
      // 4-way split-k sum over lane bits 0-1 via DPP (pure VALU)
      d0 += dpp_mov<0xB1>(d0);
      d1 += dpp_mov<0xB1>(d1);
      d0 += dpp_mov<0x4E>(d0);
      d1 += dpp_mov<0x4E>(d1);

      const float f0 = d0 + u.x;  // gamma folded into A'
      const float f1 = d1 + u.y;
      // tanh(f) = 1 - 2/(e^{2f}+1); e^{2f} = 2^(f*2/ln2); inf-safe
      const float e0 = exp2f(f0 * 2.8853900817779268f);
      const float e1 = exp2f(f1 * 2.8853900817779268f);
      const float th0 = fmaf(-2.0f, __builtin_amdgcn_rcpf(e0 + 1.0f), 1.0f);
      const float th1 = fmaf(-2.0f, __builtin_amdgcn_rcpf(e1 + 1.0f), 1.0f);
      s.x = fmaf(EPS, th0, s.x);
      s.y = fmaf(EPS, th1, s.y);

      if (kc == 0) {
        *(float2*)(outc + (size_t)(tc + tt) * WIDTH) = s;  // overwrite u slot
        *(float2*)&sL[p ^ 1][c0] = s;
      }
      LDS_BARRIER();  // lgkm-only drain; globals stay in flight
    }
  }

  if (kc == 0) *(float2*)(finals + (size_t)b * WIDTH + c0) = s;
}

extern "C" void kernel_launch(void* const* d_in, const int* in_sizes, int n_in,
                              void* d_out, int out_size, void* d_ws,
                              size_t ws_size, hipStream_t stream) {
  const float* x = (const float*)d_in[0];
  const float* init = (const float*)d_in[1];
  const float* W = (const float*)d_in[2];
  const float* V = (const float*)d_in[3];
  const float* bias = (const float*)d_in[4];

  float* out = (float*)d_out;
  float* finals = out + (size_t)B_DIM * T_DIM * WIDTH;

  proj_kernel<<<PJ_GRID, 256, 0, stream>>>(x, V, bias, out);
  rnn_kernel<<<B_DIM, 256, 0, stream>>>(W, init, out, finals);
}